// Round 7
// baseline (299.187 us; speedup 1.0000x reference)
//
#include <hip/hip_runtime.h>

// GridPoolingLayer: per-cell mean pooling; cells are rectangles from rising
// edges of h_mask/v_mask. H=W=768, C=64, fp32.
//
// R7: UNIFORM-QUANTUM design. Previous rounds (block-per-cell, wave-per-cell,
// block-per-strip) all plateaued ~102us because per-quantum cost was
// proportional to data-dependent segment sizes (occupancy counters showed
// drain tails). Here every block does identical work:
//   prep      : zero means[] + analytic inv_area[] (no atomic counts needed).
//   tile_pool : 2304 identical 8x32-px tiles; coalesced read; per-rowseg-run
//               register colsums -> LDS colseg reduce -> unsafeAtomicAdd
//               (native global_atomic_add_f32) into means[cell][cq].
//               ~4M spread scalar atomics over 9.5MB (not R3's 1 counter).
//   finalize  : means *= inv_area  (9.5MB, L2-resident).
//   bcast     : one block per image row (uniform): gather means, stream out.

#define GH 768
#define GW 768
#define MAXSEG 385       // alternating mask: 384 rising edges -> 385 segments
#define ROWQ (GW * 16)   // float4 per image row = 12288
#define TH 8             // tile rows
#define TW 32            // tile cols (px)

enum {
    OFF_ROWSTART = 0,
    OFF_ROWEND   = OFF_ROWSTART + MAXSEG,
    OFF_COLSTART = OFF_ROWEND + MAXSEG,
    OFF_COLEND   = OFF_COLSTART + MAXSEG,
    OFF_NROWS    = OFF_COLEND + MAXSEG,
    OFF_NCOLS,
    OFF_RID,                        // 768 per-pixel row segment ids
    OFF_CID = OFF_RID + GH,         // 768 per-pixel col segment ids
    OFF_END = OFF_CID + GW,
};

#define MEANS_OFF_BYTES 16384
#define MEANS_CAP_F4    ((size_t)MAXSEG * MAXSEG * 16)           // 2.37M float4
#define INV_OFF_BYTES   (MEANS_OFF_BYTES + MEANS_CAP_F4 * 16)    // ~38 MB in
#define WS_NEED_BYTES   (INV_OFF_BYTES + (size_t)MAXSEG * MAXSEG * 4)

__device__ __forceinline__ void acc4(float4& a, const float4 v) {
    a.x += v.x; a.y += v.y; a.z += v.z; a.w += v.w;
}

__global__ __launch_bounds__(768) void seg_scan(const int* __restrict__ h_mask,
                                                const int* __restrict__ v_mask,
                                                int* __restrict__ ws) {
    __shared__ int s[GH];
    const int i = threadIdx.x;
    const bool is_row = (blockIdx.x == 0);
    const int* m = is_row ? h_mask : v_mask;

    int rising = 0;
    if (i > 0) rising = (m[i] == 1 && m[i - 1] == 0) ? 1 : 0;  // rising[0] forced 0
    s[i] = rising;
    __syncthreads();

    for (int off = 1; off < GH; off <<= 1) {
        int add = (i >= off) ? s[i - off] : 0;
        __syncthreads();
        s[i] += add;
        __syncthreads();
    }

    const int seg  = s[i];
    const int segL = (i == 0)      ? -1 : s[i - 1];
    const int segR = (i == GH - 1) ? -2 : s[i + 1];

    int* start = ws + (is_row ? OFF_ROWSTART : OFF_COLSTART);
    int* end   = ws + (is_row ? OFF_ROWEND   : OFF_COLEND);
    if (seg != segL) start[seg] = i;
    if (seg != segR) end[seg]   = i + 1;
    ws[(is_row ? OFF_RID : OFF_CID) + i] = seg;
    if (i == GH - 1) ws[is_row ? OFF_NROWS : OFF_NCOLS] = seg + 1;
}

// ---- prep: zero means (only the used range) + analytic inv_area ----
__global__ __launch_bounds__(256) void prep(float4* __restrict__ means,
                                            float* __restrict__ inv,
                                            const int* __restrict__ ws) {
    const int nrows = ws[OFF_NROWS];
    const int ncols = ws[OFF_NCOLS];
    const int ncells = nrows * ncols;
    const int stride = gridDim.x * blockDim.x;
    const float4 z = make_float4(0.f, 0.f, 0.f, 0.f);
    for (int v = blockIdx.x * blockDim.x + threadIdx.x; v < ncells * 16; v += stride)
        means[v] = z;
    for (int v = blockIdx.x * blockDim.x + threadIdx.x; v < ncells; v += stride) {
        const int r = v / ncols;
        const int s = v - r * ncols;
        const int h = ws[OFF_ROWEND + r] - ws[OFF_ROWSTART + r];
        const int w = ws[OFF_COLEND + s] - ws[OFF_COLSTART + s];
        inv[v] = 1.0f / (float)(h * w);   // area >= 1 always
    }
}

// ---- tile_pool: identical 8x32 tiles; atomic partial sums into means ----
__global__ __launch_bounds__(256) void tile_pool(const float4* __restrict__ in,
                                                 float4* __restrict__ means,
                                                 const int* __restrict__ ws) {
    const int tx0 = blockIdx.x * TW;   // 0..23 tiles
    const int ty0 = blockIdx.y * TH;   // 0..95 tiles
    const int tid = threadIdx.x;

    __shared__ int scid[TW];
    __shared__ int srid[TH];
    __shared__ float4 colsum[TW * 16];   // 8 KB

    if (tid < TW) scid[tid] = ws[OFF_CID + tx0 + tid];
    if (tid < TH) srid[tid] = ws[OFF_RID + ty0 + tid];
    __syncthreads();

    const int ncols   = ws[OFF_NCOLS];
    const int s_first = scid[0];
    const int s_last  = scid[TW - 1];
    const int nst     = s_last - s_first + 1;   // colsegs intersecting tile

    const int u0 = tid, u1 = tid + 256;         // slots: x = u>>4, cq = u&15

    int y = 0;
    while (y < TH) {
        const int r = srid[y];                  // block-uniform rowseg run
        int ye = y + 1;
        while (ye < TH && srid[ye] == r) ++ye;

        float4 a0 = make_float4(0.f,0.f,0.f,0.f), a1 = a0;
        for (int yy = y; yy < ye; ++yy) {
            const size_t base = ((size_t)(ty0 + yy) * GW + tx0) * 16;
            acc4(a0, in[base + u0]);
            acc4(a1, in[base + u1]);
        }
        colsum[u0] = a0;
        colsum[u1] = a1;
        __syncthreads();

        for (int v = tid; v < nst * 16; v += 256) {
            const int sl = v >> 4, cq = v & 15;
            const int sg = s_first + sl;
            int gx0 = ws[OFF_COLSTART + sg] - tx0; if (gx0 < 0) gx0 = 0;
            int gx1 = ws[OFF_COLEND + sg]   - tx0; if (gx1 > TW) gx1 = TW;
            float4 a = make_float4(0.f,0.f,0.f,0.f);
            for (int x = gx0; x < gx1; ++x) acc4(a, colsum[x * 16 + cq]);
            float* dst = (float*)&means[((size_t)r * ncols + sg) * 16 + cq];
            unsafeAtomicAdd(dst + 0, a.x);
            unsafeAtomicAdd(dst + 1, a.y);
            unsafeAtomicAdd(dst + 2, a.z);
            unsafeAtomicAdd(dst + 3, a.w);
        }
        __syncthreads();
        y = ye;
    }
}

// ---- finalize: means *= inv_area ----
__global__ __launch_bounds__(256) void finalize(float4* __restrict__ means,
                                                const float* __restrict__ inv,
                                                const int* __restrict__ ws) {
    const int ncells = ws[OFF_NROWS] * ws[OFF_NCOLS];
    const int stride = gridDim.x * blockDim.x;
    for (int v = blockIdx.x * blockDim.x + threadIdx.x; v < ncells * 16; v += stride) {
        const float s = inv[v >> 4];
        float4 m = means[v];
        m.x *= s; m.y *= s; m.z *= s; m.w *= s;
        means[v] = m;
    }
}

// ---- bcast: one block per image row; pure streaming write ----
__global__ __launch_bounds__(256) void bcast(const float4* __restrict__ means,
                                             float4* __restrict__ out,
                                             const int* __restrict__ ws) {
    __shared__ int scell[GW];
    const int y   = blockIdx.x;
    const int tid = threadIdx.x;
    const int rid   = ws[OFF_RID + y];
    const int ncols = ws[OFF_NCOLS];
    for (int x = tid; x < GW; x += 256)
        scell[x] = rid * ncols + ws[OFF_CID + x];
    __syncthreads();

    float4* orow = out + (size_t)y * ROWQ;
    #pragma unroll 4
    for (int u = tid; u < ROWQ; u += 256) {
        orow[u] = means[(size_t)scell[u >> 4] * 16 + (u & 15)];
    }
}

// ---- Fallback: R2 static wave-per-cell (only if ws too small) ----
__global__ __launch_bounds__(256) void cell_pool(const float4* __restrict__ in,
                                                 float4* __restrict__ out,
                                                 const int* __restrict__ ws) {
    const int nrows  = ws[OFF_NROWS];
    const int ncols  = ws[OFF_NCOLS];
    const int ncells = nrows * ncols;
    const int wave   = blockIdx.x * 4 + (threadIdx.x >> 6);
    const int nwaves = gridDim.x * 4;
    const int lane   = threadIdx.x & 63;
    const int pg     = lane >> 4;
    const int cq     = lane & 15;

    for (int cell = wave; cell < ncells; cell += nwaves) {
        const int br = cell / ncols;
        const int bc = cell - br * ncols;
        const int y0 = ws[OFF_ROWSTART + br];
        const int y1 = ws[OFF_ROWEND + br];
        const int x0 = ws[OFF_COLSTART + bc];
        const int x1 = ws[OFF_COLEND + bc];
        float4 a = make_float4(0.f,0.f,0.f,0.f);
        for (int yy = y0; yy < y1; ++yy) {
            const size_t rb = (size_t)yy * ROWQ + cq;
            for (int x = x0 + pg; x < x1; x += 4)
                acc4(a, in[rb + (size_t)x * 16]);
        }
        #pragma unroll
        for (int msk = 16; msk < 64; msk <<= 1) {
            a.x += __shfl_xor(a.x, msk, 64);
            a.y += __shfl_xor(a.y, msk, 64);
            a.z += __shfl_xor(a.z, msk, 64);
            a.w += __shfl_xor(a.w, msk, 64);
        }
        const float area = (float)((y1 - y0) * (x1 - x0));
        float4 mn = make_float4(a.x / area, a.y / area, a.z / area, a.w / area);
        for (int yy = y0; yy < y1; ++yy) {
            const size_t rb = (size_t)yy * ROWQ + cq;
            for (int x = x0 + pg; x < x1; x += 4)
                out[rb + (size_t)x * 16] = mn;
        }
    }
}

extern "C" void kernel_launch(void* const* d_in, const int* in_sizes, int n_in,
                              void* d_out, int out_size, void* d_ws, size_t ws_size,
                              hipStream_t stream) {
    const float* in  = (const float*)d_in[0];   // [1,768,768,64] fp32
    const int* hmask = (const int*)d_in[1];     // [1,768] int32
    const int* vmask = (const int*)d_in[2];     // [1,768] int32
    float* out = (float*)d_out;                 // [1,768,768,64] fp32
    int* ws = (int*)d_ws;

    seg_scan<<<2, GH, 0, stream>>>(hmask, vmask, ws);

    if (ws_size >= WS_NEED_BYTES) {
        float4* means = (float4*)((char*)d_ws + MEANS_OFF_BYTES);
        float* inv    = (float*)((char*)d_ws + INV_OFF_BYTES);
        prep<<<1024, 256, 0, stream>>>(means, inv, ws);
        dim3 tg(GW / TW, GH / TH);   // (24, 96) identical tiles
        tile_pool<<<tg, 256, 0, stream>>>((const float4*)in, means, ws);
        finalize<<<512, 256, 0, stream>>>(means, inv, ws);
        bcast<<<GH, 256, 0, stream>>>(means, (float4*)out, ws);
    } else {
        cell_pool<<<2048, 256, 0, stream>>>((const float4*)in, (float4*)out, ws);
    }
}